// Round 8
// baseline (68.459 us; speedup 1.0000x reference)
//
#include <hip/hip_runtime.h>
#include <stdint.h>

// LDDMM Hamiltonian evolution via MFMA (flash-attention-style).
//   out0 = -dH/dpos = 400 * sum_j K_ij (m_i.m_j)(x_i - x_j)
//   out1 =  dH/dmom = 2   * sum_j K_ij m_j ,  K = exp(-100*||x_i-x_j||^2)
//
// arg_ij = 2<Xi,Xj> - |Xi|^2 - |Xj|^2 (X = sqrt(100 log2 e) x) is a Gram
// matrix -> mfma_f32_16x16x32_bf16 with a 24-slot exact bf16-split K-pack
// (h+l+r for X, 3-way split for D=-|X|^2; arg err ~2e-5). m_i.m_j = second
// Gram MFMA. VALU does only exp2 + w=e*m + bf16 packing. Accumulations
// G=P@mom and [Swx|Sw]=W@[x|1] go through MFMA again (P/W bounced through
// LDS from C-frag layout (col=lane&15,row=(lane>>4)*4+reg, m89-verified)
// into B-frag layout (col=lane&15, k=(lane>>4)*8+e consecutive, m97
// pattern); mom/x row-split (h,l) for exactness; W split (wh,wl) into
// duplicated K-slots. 8 i-panels/wave amortize A-frag loads.

typedef unsigned short ushort;
typedef unsigned int uint;
typedef short  s16x8 __attribute__((ext_vector_type(8)));
typedef float  f32x4 __attribute__((ext_vector_type(4)));
typedef uint   u32x2 __attribute__((ext_vector_type(2)));
typedef uint   u32x4 __attribute__((ext_vector_type(4)));

constexpr int BLOCK  = 256;
constexpr int WAVES  = 4;
constexpr int PANELS = 8;                 // i-panels (16 i each) per wave
constexpr int IPW    = PANELS * 16;       // 128 i per wave
constexpr int IPB    = WAVES * IPW;       // 512 i per block

constexpr double S_Dd      = 12.011224087864498;   // sqrt(100*log2(e))
constexpr float  SCALE_POS = (float)S_Dd;

__device__ __forceinline__ float fast_exp2(float x) {
#if __has_builtin(__builtin_amdgcn_exp2f)
    return __builtin_amdgcn_exp2f(x);
#else
    return exp2f(x);
#endif
}
__device__ __forceinline__ ushort bf16r(float f) {      // RNE f32->bf16
    uint u = __float_as_uint(f);
    uint r = u + 0x7FFFu + ((u >> 16) & 1u);
    return (ushort)(r >> 16);
}
__device__ __forceinline__ float bf2f(ushort s) {
    return __uint_as_float(((uint)s) << 16);
}
__device__ __forceinline__ uint cvtpk(float a, float b) {  // lo=bf16(a), hi=bf16(b)
    uint r;
    asm("v_cvt_pk_bf16_f32 %0, %1, %2" : "=v"(r) : "v"(a), "v"(b));
    return r;
}
__device__ __forceinline__ uint wsplit(float w) {       // (wh, wl) pair, wh+wl ~= w
    float wh = __uint_as_float(__float_as_uint(w) & 0xFFFF0000u);
    return cvtpk(wh, w - wh);
}

// ---------------- prep: build all bf16 packs ----------------
__global__ __launch_bounds__(BLOCK)
void lddmm_prep(const float* __restrict__ mom, const float* __restrict__ pos,
                ushort* __restrict__ pSA, ushort* __restrict__ pSB,
                ushort* __restrict__ pMA, ushort* __restrict__ pMB,
                ushort* __restrict__ momTA, ushort* __restrict__ xTFA, int N)
{
    const int n = blockIdx.x * BLOCK + threadIdx.x;
    if (n >= N) return;
    float x[3], m[3];
    #pragma unroll
    for (int c = 0; c < 3; ++c) { x[c] = pos[3 * n + c]; m[c] = mom[3 * n + c]; }

    ushort h[3], l[3], h2[3], l2[3], r2[3];
    float  D = 0.f;
    #pragma unroll
    for (int c = 0; c < 3; ++c) {
        const float X = SCALE_POS * x[c];
        h[c] = bf16r(X);                  const float hf = bf2f(h[c]);
        l[c] = bf16r(X - hf);             const float lf = bf2f(l[c]);
        const float rf = bf2f(bf16r(X - hf - lf));
        h2[c] = bf16r(2.f * hf);
        l2[c] = bf16r(2.f * lf);
        r2[c] = bf16r(2.f * rf);
        D -= X * X;
    }
    const ushort Dh = bf16r(D);           const float Dhf = bf2f(Dh);
    const ushort Dl = bf16r(D - Dhf);     const float Dlf = bf2f(Dl);
    const ushort Dr = bf16r(D - Dhf - Dlf);
    ushort hm[3], lm[3], xh[3], xl[3];
    #pragma unroll
    for (int c = 0; c < 3; ++c) {
        hm[c] = bf16r(m[c]); lm[c] = bf16r(m[c] - bf2f(hm[c]));
        xh[c] = bf16r(x[c]); xl[c] = bf16r(x[c] - bf2f(xh[c]));
    }
    const ushort ONE = 0x3F80;

    // S-pack: sum_k A_k B_k = 2<(h+l+r)_j,(h+l+r)_i> + Dj + Di  (exact to ~2e-5)
    ushort sa[32] = {}; ushort sb[32] = {};
    #pragma unroll
    for (int c = 0; c < 3; ++c) {
        sa[0+c]=h2[c];  sb[0+c]=h[c];     // 2h_j * h_i
        sa[3+c]=l2[c];  sb[3+c]=h[c];     // 2l_j * h_i
        sa[6+c]=h2[c];  sb[6+c]=l[c];     // 2h_j * l_i
        sa[9+c]=l2[c];  sb[9+c]=l[c];     // 2l_j * l_i
        sa[18+c]=r2[c]; sb[18+c]=h[c];    // 2r_j * h_i
        sa[21+c]=h[c];  sb[21+c]=r2[c];   // h_j * 2r_i
    }
    sa[12]=Dh; sa[13]=Dl; sa[14]=Dr; sb[12]=ONE; sb[13]=ONE; sb[14]=ONE;  // Dj
    sa[15]=ONE; sa[16]=ONE; sa[17]=ONE; sb[15]=Dh; sb[16]=Dl; sb[17]=Dr;  // Di

    ushort ma[32] = {}; ushort mb[32] = {};
    #pragma unroll
    for (int c = 0; c < 3; ++c) {
        ma[0+c]=hm[c]; mb[0+c]=hm[c];
        ma[3+c]=lm[c]; mb[3+c]=hm[c];
        ma[6+c]=hm[c]; mb[6+c]=lm[c];
        ma[9+c]=lm[c]; mb[9+c]=lm[c];
    }

    u32x4* oSA = (u32x4*)(pSA + (size_t)n * 32);
    u32x4* oSB = (u32x4*)(pSB + (size_t)n * 32);
    u32x4* oMA = (u32x4*)(pMA + (size_t)n * 32);
    u32x4* oMB = (u32x4*)(pMB + (size_t)n * 32);
    #pragma unroll
    for (int k = 0; k < 4; ++k) {
        oSA[k] = ((u32x4*)sa)[k]; oSB[k] = ((u32x4*)sb)[k];
        oMA[k] = ((u32x4*)ma)[k]; oMB[k] = ((u32x4*)mb)[k];
    }

    // momT A-tile: [tile=n>>5][row][col=n&31]; rows 0-2 = hm, 3-5 = lm (rest memset 0)
    {
        ushort* q = momTA + (size_t)(n >> 5) * 512 + (n & 31);
        q[0*32]=hm[0]; q[1*32]=hm[1]; q[2*32]=hm[2];
        q[3*32]=lm[0]; q[4*32]=lm[1]; q[5*32]=lm[2];
    }
    // xT/ones A-tile (F): [tile=n>>4][row][2*(n&15)+p]; rows 0-2=xh, 3=1, 4-6=xl
    {
        ushort* q = xTFA + (size_t)(n >> 4) * 512 + 2 * (n & 15);
        #pragma unroll
        for (int p = 0; p < 2; ++p) {
            q[0*32+p]=xh[0]; q[1*32+p]=xh[1]; q[2*32+p]=xh[2];
            q[3*32+p]=ONE;
            q[4*32+p]=xl[0]; q[5*32+p]=xl[1]; q[6*32+p]=xl[2];
        }
    }
}

// ---------------- main: MFMA over 16i x 32j super-tiles ----------------
__global__ __launch_bounds__(BLOCK, 2)
void lddmm_mfma(const ushort* __restrict__ pSA, const ushort* __restrict__ pSB,
                const ushort* __restrict__ pMA, const ushort* __restrict__ pMB,
                const ushort* __restrict__ momTA, const ushort* __restrict__ xTFA,
                float* __restrict__ partG, float* __restrict__ partF,
                int N, int G)
{
    __shared__ ushort bounce[WAVES][1792];   // per wave: P[16][40] @0, W[16][72] @640

    const int tid  = threadIdx.x;
    const int w    = tid >> 6;
    const int lane = tid & 63;
    const int lrow = lane & 15;
    const int lgrp = lane >> 4;

    const int bid  = blockIdx.x;
    const int seg  = bid % G;
    const int iblk = bid / G;
    const int segLen = N / G;            // multiple of 32
    const int jseg0  = seg * segLen;
    const int nsup   = segLen >> 5;

    // one-time B-fragments for this wave's 8 i-panels
    s16x8 SBf[PANELS], MBf[PANELS];
    int ibase[PANELS];
    #pragma unroll
    for (int p = 0; p < PANELS; ++p) {
        const int i = iblk * IPB + w * IPW + p * 16 + lrow;
        ibase[p] = i;
        SBf[p] = *(const s16x8*)(pSB + (size_t)i * 32 + lgrp * 8);
        MBf[p] = *(const s16x8*)(pMB + (size_t)i * 32 + lgrp * 8);
    }
    const f32x4 z = {0.f, 0.f, 0.f, 0.f};
    f32x4 accG[PANELS], accF[PANELS];
    #pragma unroll
    for (int p = 0; p < PANELS; ++p) { accG[p] = z; accF[p] = z; }

    ushort* Pb = &bounce[w][0];
    ushort* Wb = &bounce[w][640];
    const uint pWr = lrow * 40 + lgrp * 4;   // ushort idx; +h*16
    const uint wWr = lrow * 72 + lgrp * 8;   // +h*32
    const uint pRd = lrow * 40 + lgrp * 8;
    const uint wRd = lrow * 72 + lgrp * 8;   // +h*32

    const ushort* saP = pSA + (size_t)jseg0 * 32 + lrow * 32 + lgrp * 8;
    const ushort* maP = pMA + (size_t)jseg0 * 32 + lrow * 32 + lgrp * 8;
    const ushort* mtP = momTA + (size_t)(jseg0 >> 5) * 512 + lrow * 32 + lgrp * 8;
    const ushort* faP = xTFA  + (size_t)(jseg0 >> 4) * 512 + lrow * 32 + lgrp * 8;

    for (int s = 0; s < nsup; ++s) {
        const s16x8 sa0 = *(const s16x8*)(saP);
        const s16x8 sa1 = *(const s16x8*)(saP + 512);
        const s16x8 ma0 = *(const s16x8*)(maP);
        const s16x8 ma1 = *(const s16x8*)(maP + 512);
        const s16x8 mta = *(const s16x8*)(mtP);
        const s16x8 fa0 = *(const s16x8*)(faP);
        const s16x8 fa1 = *(const s16x8*)(faP + 512);
        saP += 1024; maP += 1024; mtP += 512; faP += 1024;

        #pragma unroll
        for (int p = 0; p < PANELS; ++p) {
            f32x4 s0 = __builtin_amdgcn_mfma_f32_16x16x32_bf16(sa0, SBf[p], z, 0, 0, 0);
            f32x4 m0 = __builtin_amdgcn_mfma_f32_16x16x32_bf16(ma0, MBf[p], z, 0, 0, 0);
            f32x4 s1 = __builtin_amdgcn_mfma_f32_16x16x32_bf16(sa1, SBf[p], z, 0, 0, 0);
            f32x4 m1 = __builtin_amdgcn_mfma_f32_16x16x32_bf16(ma1, MBf[p], z, 0, 0, 0);

            // half 0
            {
                const float e0 = fast_exp2(s0[0]), e1 = fast_exp2(s0[1]);
                const float e2 = fast_exp2(s0[2]), e3 = fast_exp2(s0[3]);
                const float w0 = e0 * m0[0], w1 = e1 * m0[1];
                const float w2 = e2 * m0[2], w3 = e3 * m0[3];
                u32x2 pp; pp[0] = cvtpk(e0, e1); pp[1] = cvtpk(e2, e3);
                *(u32x2*)(Pb + pWr) = pp;
                u32x4 ww; ww[0] = wsplit(w0); ww[1] = wsplit(w1);
                ww[2] = wsplit(w2); ww[3] = wsplit(w3);
                *(u32x4*)(Wb + wWr) = ww;
            }
            // half 1
            {
                const float e0 = fast_exp2(s1[0]), e1 = fast_exp2(s1[1]);
                const float e2 = fast_exp2(s1[2]), e3 = fast_exp2(s1[3]);
                const float w0 = e0 * m1[0], w1 = e1 * m1[1];
                const float w2 = e2 * m1[2], w3 = e3 * m1[3];
                u32x2 pp; pp[0] = cvtpk(e0, e1); pp[1] = cvtpk(e2, e3);
                *(u32x2*)(Pb + pWr + 16) = pp;
                u32x4 ww; ww[0] = wsplit(w0); ww[1] = wsplit(w1);
                ww[2] = wsplit(w2); ww[3] = wsplit(w3);
                *(u32x4*)(Wb + wWr + 32) = ww;
            }
            // bounce back as B-fragments (compiler orders LDS RAW/WAR via lgkmcnt)
            const s16x8 pbf = *(const s16x8*)(Pb + pRd);
            const s16x8 wb0 = *(const s16x8*)(Wb + wRd);
            const s16x8 wb1 = *(const s16x8*)(Wb + wRd + 32);
            accG[p] = __builtin_amdgcn_mfma_f32_16x16x32_bf16(mta, pbf, accG[p], 0, 0, 0);
            accF[p] = __builtin_amdgcn_mfma_f32_16x16x32_bf16(fa0, wb0, accF[p], 0, 0, 0);
            accF[p] = __builtin_amdgcn_mfma_f32_16x16x32_bf16(fa1, wb1, accF[p], 0, 0, 0);
        }
    }

    // epilogue: [seg][rowgroup=lgrp][i][4] fully coalesced f32x4 stores
    #pragma unroll
    for (int p = 0; p < PANELS; ++p) {
        const size_t off = ((size_t)(seg * 4 + lgrp) * N + ibase[p]) * 4;
        *(f32x4*)(partG + off) = accG[p];
        *(f32x4*)(partF + off) = accF[p];
    }
}

// ---------------- reduce ----------------
__global__ __launch_bounds__(BLOCK)
void lddmm_reduce(const float* __restrict__ partG, const float* __restrict__ partF,
                  const float* __restrict__ pos, float* __restrict__ out, int N, int G)
{
    const int i = blockIdx.x * BLOCK + threadIdx.x;
    if (i >= N) return;
    f32x4 g0 = {0,0,0,0}, g1 = {0,0,0,0}, f0 = {0,0,0,0}, f1 = {0,0,0,0};
    for (int seg = 0; seg < G; ++seg) {
        const size_t b0 = ((size_t)(seg * 4 + 0) * N + i) * 4;
        const size_t b1 = ((size_t)(seg * 4 + 1) * N + i) * 4;
        g0 += *(const f32x4*)(partG + b0);
        g1 += *(const f32x4*)(partG + b1);
        f0 += *(const f32x4*)(partF + b0);
        f1 += *(const f32x4*)(partF + b1);
    }
    // G rows: [Ghx,Ghy,Ghz,Glx | Gly,Glz,0,0]; F rows: [Swxh(3),Sw | Swxl(3),0]
    const float Gx = 2.f * (g0[0] + g0[3]);
    const float Gy = 2.f * (g0[1] + g1[0]);
    const float Gz = 2.f * (g0[2] + g1[1]);
    const float Sw = f0[3];
    float F[3];
    #pragma unroll
    for (int c = 0; c < 3; ++c)
        F[c] = 400.f * (pos[3 * i + c] * Sw - (f0[c] + f1[c]));
    out[3 * i + 0] = F[0]; out[3 * i + 1] = F[1]; out[3 * i + 2] = F[2];
    float* o2 = out + (size_t)N * 3;
    o2[3 * i + 0] = Gx; o2[3 * i + 1] = Gy; o2[3 * i + 2] = Gz;
}

extern "C" void kernel_launch(void* const* d_in, const int* in_sizes, int n_in,
                              void* d_out, int out_size, void* d_ws, size_t ws_size,
                              hipStream_t stream) {
    const float* mom = (const float*)d_in[0];
    const float* pos = (const float*)d_in[1];
    float* out = (float*)d_out;
    const int N = in_sizes[0] / 3;          // 8192 (code assumes N % 512 == 0)

    char* base = (char*)d_ws;
    size_t off = 0;
    ushort* pSA   = (ushort*)(base + off); off += (size_t)N * 64;
    ushort* pSB   = (ushort*)(base + off); off += (size_t)N * 64;
    ushort* pMA   = (ushort*)(base + off); off += (size_t)N * 64;
    ushort* pMB   = (ushort*)(base + off); off += (size_t)N * 64;
    ushort* momTA = (ushort*)(base + off); off += (size_t)N * 32;   // [N/32][16][32]
    ushort* xTFA  = (ushort*)(base + off); off += (size_t)N * 64;   // [N/16][16][32]

    int G = 64;
    while (G > 1 && ((N / G) % 32 != 0 ||
           off + 2 * (size_t)G * 4 * N * 16 > ws_size)) G >>= 1;
    float* partG = (float*)(base + off); off += (size_t)G * 4 * N * 16;
    float* partF = (float*)(base + off);

    // zero the A-tile arrays (prep fills only the nonzero rows)
    hipMemsetAsync(momTA, 0, (size_t)N * 96, stream);

    const int nb = (N + BLOCK - 1) / BLOCK;
    lddmm_prep<<<dim3(nb), dim3(BLOCK), 0, stream>>>(mom, pos, pSA, pSB, pMA, pMB,
                                                     momTA, xTFA, N);
    lddmm_mfma<<<dim3((N / IPB) * G), dim3(BLOCK), 0, stream>>>(
        pSA, pSB, pMA, pMB, momTA, xTFA, partG, partF, N, G);
    lddmm_reduce<<<dim3(nb), dim3(BLOCK), 0, stream>>>(partG, partF, pos, out, N, G);
}

// Round 9
// 46.959 us; speedup vs baseline: 1.4578x; 1.4578x over previous
//
#include <hip/hip_runtime.h>
#include <stdint.h>

// LDDMM Hamiltonian evolution via MFMA (flash-attention-style).
//   out0 = -dH/dpos = 400 * sum_j K_ij (m_i.m_j)(x_i - x_j)
//   out1 =  dH/dmom = 2   * sum_j K_ij m_j ,  K = exp(-100*||x_i-x_j||^2)
//
// arg_ij = 2<Xi,Xj> - |Xi|^2 - |Xj|^2 is a Gram matrix -> 16x16x32 bf16
// MFMA with exact bf16-split K-packs (validated R8, absmax 0.0156).
// R9: kill the partial-buffer blowup (R8 stored 128B/(seg,i) = 67MB W+R).
// Epilogue shfl_xor(16) folds row-group1 into row-group0 and applies the
// final formulas -> 6 floats/(seg,i) (G=32: 6.3MB round-trip). Prep writes
// zero A-rows itself (memset dispatch dropped). launch_bounds(256,2).

typedef unsigned short ushort;
typedef unsigned int uint;
typedef short  s16x8 __attribute__((ext_vector_type(8)));
typedef float  f32x4 __attribute__((ext_vector_type(4)));
typedef uint   u32x2 __attribute__((ext_vector_type(2)));
typedef uint   u32x4 __attribute__((ext_vector_type(4)));

constexpr int BLOCK  = 256;
constexpr int WAVES  = 4;
constexpr int PANELS = 8;                 // i-panels (16 i each) per wave
constexpr int IPW    = PANELS * 16;       // 128 i per wave
constexpr int IPB    = WAVES * IPW;       // 512 i per block

constexpr double S_Dd      = 12.011224087864498;   // sqrt(100*log2(e))
constexpr float  SCALE_POS = (float)S_Dd;

__device__ __forceinline__ float fast_exp2(float x) {
#if __has_builtin(__builtin_amdgcn_exp2f)
    return __builtin_amdgcn_exp2f(x);
#else
    return exp2f(x);
#endif
}
__device__ __forceinline__ ushort bf16r(float f) {      // RNE f32->bf16
    uint u = __float_as_uint(f);
    uint r = u + 0x7FFFu + ((u >> 16) & 1u);
    return (ushort)(r >> 16);
}
__device__ __forceinline__ float bf2f(ushort s) {
    return __uint_as_float(((uint)s) << 16);
}
__device__ __forceinline__ uint cvtpk(float a, float b) {  // lo=bf16(a), hi=bf16(b)
    uint r;
    asm("v_cvt_pk_bf16_f32 %0, %1, %2" : "=v"(r) : "v"(a), "v"(b));
    return r;
}
__device__ __forceinline__ uint wsplit(float w) {       // (wh, wl) pair, wh+wl ~= w
    float wh = __uint_as_float(__float_as_uint(w) & 0xFFFF0000u);
    return cvtpk(wh, w - wh);
}

// ---------------- prep: build all bf16 packs ----------------
__global__ __launch_bounds__(BLOCK)
void lddmm_prep(const float* __restrict__ mom, const float* __restrict__ pos,
                ushort* __restrict__ pSA, ushort* __restrict__ pSB,
                ushort* __restrict__ pMA, ushort* __restrict__ pMB,
                ushort* __restrict__ momTA, ushort* __restrict__ xTFA, int N)
{
    const int n = blockIdx.x * BLOCK + threadIdx.x;
    if (n >= N) return;
    float x[3], m[3];
    #pragma unroll
    for (int c = 0; c < 3; ++c) { x[c] = pos[3 * n + c]; m[c] = mom[3 * n + c]; }

    ushort h[3], l[3], h2[3], l2[3], r2[3];
    float  D = 0.f;
    #pragma unroll
    for (int c = 0; c < 3; ++c) {
        const float X = SCALE_POS * x[c];
        h[c] = bf16r(X);                  const float hf = bf2f(h[c]);
        l[c] = bf16r(X - hf);             const float lf = bf2f(l[c]);
        const float rf = bf2f(bf16r(X - hf - lf));
        h2[c] = bf16r(2.f * hf);
        l2[c] = bf16r(2.f * lf);
        r2[c] = bf16r(2.f * rf);
        D -= X * X;
    }
    const ushort Dh = bf16r(D);           const float Dhf = bf2f(Dh);
    const ushort Dl = bf16r(D - Dhf);     const float Dlf = bf2f(Dl);
    const ushort Dr = bf16r(D - Dhf - Dlf);
    ushort hm[3], lm[3], xh[3], xl[3];
    #pragma unroll
    for (int c = 0; c < 3; ++c) {
        hm[c] = bf16r(m[c]); lm[c] = bf16r(m[c] - bf2f(hm[c]));
        xh[c] = bf16r(x[c]); xl[c] = bf16r(x[c] - bf2f(xh[c]));
    }
    const ushort ONE = 0x3F80;

    // S-pack: sum_k A_k B_k = 2<(h+l+r)_j,(h+l+r)_i> + Dj + Di  (err ~2e-5)
    ushort sa[32] = {}; ushort sb[32] = {};
    #pragma unroll
    for (int c = 0; c < 3; ++c) {
        sa[0+c]=h2[c];  sb[0+c]=h[c];
        sa[3+c]=l2[c];  sb[3+c]=h[c];
        sa[6+c]=h2[c];  sb[6+c]=l[c];
        sa[9+c]=l2[c];  sb[9+c]=l[c];
        sa[18+c]=r2[c]; sb[18+c]=h[c];
        sa[21+c]=h[c];  sb[21+c]=r2[c];
    }
    sa[12]=Dh; sa[13]=Dl; sa[14]=Dr; sb[12]=ONE; sb[13]=ONE; sb[14]=ONE;
    sa[15]=ONE; sa[16]=ONE; sa[17]=ONE; sb[15]=Dh; sb[16]=Dl; sb[17]=Dr;

    ushort ma[32] = {}; ushort mb[32] = {};
    #pragma unroll
    for (int c = 0; c < 3; ++c) {
        ma[0+c]=hm[c]; mb[0+c]=hm[c];
        ma[3+c]=lm[c]; mb[3+c]=hm[c];
        ma[6+c]=hm[c]; mb[6+c]=lm[c];
        ma[9+c]=lm[c]; mb[9+c]=lm[c];
    }

    u32x4* oSA = (u32x4*)(pSA + (size_t)n * 32);
    u32x4* oSB = (u32x4*)(pSB + (size_t)n * 32);
    u32x4* oMA = (u32x4*)(pMA + (size_t)n * 32);
    u32x4* oMB = (u32x4*)(pMB + (size_t)n * 32);
    #pragma unroll
    for (int k = 0; k < 4; ++k) {
        oSA[k] = ((u32x4*)sa)[k]; oSB[k] = ((u32x4*)sb)[k];
        oMA[k] = ((u32x4*)ma)[k]; oMB[k] = ((u32x4*)mb)[k];
    }

    // momT A-tile: [tile=n>>5][row][col=n&31]; rows 0-2=hm, 3-5=lm, 6-15=0
    {
        ushort* q = momTA + (size_t)(n >> 5) * 512 + (n & 31);
        q[0*32]=hm[0]; q[1*32]=hm[1]; q[2*32]=hm[2];
        q[3*32]=lm[0]; q[4*32]=lm[1]; q[5*32]=lm[2];
        #pragma unroll
        for (int r = 6; r < 16; ++r) q[r*32] = 0;
    }
    // xT/ones A-tile: [tile=n>>4][row][2*(n&15)+p]; rows 0-2=xh, 3=1, 4-6=xl, 7-15=0
    {
        ushort* q = xTFA + (size_t)(n >> 4) * 512 + 2 * (n & 15);
        #pragma unroll
        for (int p = 0; p < 2; ++p) {
            q[0*32+p]=xh[0]; q[1*32+p]=xh[1]; q[2*32+p]=xh[2];
            q[3*32+p]=ONE;
            q[4*32+p]=xl[0]; q[5*32+p]=xl[1]; q[6*32+p]=xl[2];
            #pragma unroll
            for (int r = 7; r < 16; ++r) q[r*32+p] = 0;
        }
    }
}

// ---------------- main: MFMA over 16i x 32j super-tiles ----------------
__global__ __launch_bounds__(BLOCK, 2)
void lddmm_mfma(const ushort* __restrict__ pSA, const ushort* __restrict__ pSB,
                const ushort* __restrict__ pMA, const ushort* __restrict__ pMB,
                const ushort* __restrict__ momTA, const ushort* __restrict__ xTFA,
                const float* __restrict__ pos, float* __restrict__ part,
                int N, int G)
{
    __shared__ ushort bounce[WAVES][1792];   // per wave: P[16][40] @0, W[16][72] @640

    const int tid  = threadIdx.x;
    const int w    = tid >> 6;
    const int lane = tid & 63;
    const int lrow = lane & 15;
    const int lgrp = lane >> 4;

    const int bid  = blockIdx.x;
    const int seg  = bid % G;
    const int iblk = bid / G;
    const int segLen = N / G;            // multiple of 32
    const int jseg0  = seg * segLen;
    const int nsup   = segLen >> 5;

    s16x8 SBf[PANELS], MBf[PANELS];
    int ibase[PANELS];
    #pragma unroll
    for (int p = 0; p < PANELS; ++p) {
        const int i = iblk * IPB + w * IPW + p * 16 + lrow;
        ibase[p] = i;
        SBf[p] = *(const s16x8*)(pSB + (size_t)i * 32 + lgrp * 8);
        MBf[p] = *(const s16x8*)(pMB + (size_t)i * 32 + lgrp * 8);
    }
    const f32x4 z = {0.f, 0.f, 0.f, 0.f};
    f32x4 accG[PANELS], accF[PANELS];
    #pragma unroll
    for (int p = 0; p < PANELS; ++p) { accG[p] = z; accF[p] = z; }

    ushort* Pb = &bounce[w][0];
    ushort* Wb = &bounce[w][640];
    const uint pWr = lrow * 40 + lgrp * 4;
    const uint wWr = lrow * 72 + lgrp * 8;
    const uint pRd = lrow * 40 + lgrp * 8;
    const uint wRd = lrow * 72 + lgrp * 8;

    const ushort* saP = pSA + (size_t)jseg0 * 32 + lrow * 32 + lgrp * 8;
    const ushort* maP = pMA + (size_t)jseg0 * 32 + lrow * 32 + lgrp * 8;
    const ushort* mtP = momTA + (size_t)(jseg0 >> 5) * 512 + lrow * 32 + lgrp * 8;
    const ushort* faP = xTFA  + (size_t)(jseg0 >> 4) * 512 + lrow * 32 + lgrp * 8;

    for (int s = 0; s < nsup; ++s) {
        const s16x8 sa0 = *(const s16x8*)(saP);
        const s16x8 sa1 = *(const s16x8*)(saP + 512);
        const s16x8 ma0 = *(const s16x8*)(maP);
        const s16x8 ma1 = *(const s16x8*)(maP + 512);
        const s16x8 mta = *(const s16x8*)(mtP);
        const s16x8 fa0 = *(const s16x8*)(faP);
        const s16x8 fa1 = *(const s16x8*)(faP + 512);
        saP += 1024; maP += 1024; mtP += 512; faP += 1024;

        #pragma unroll
        for (int p = 0; p < PANELS; ++p) {
            f32x4 s0 = __builtin_amdgcn_mfma_f32_16x16x32_bf16(sa0, SBf[p], z, 0, 0, 0);
            f32x4 m0 = __builtin_amdgcn_mfma_f32_16x16x32_bf16(ma0, MBf[p], z, 0, 0, 0);
            f32x4 s1 = __builtin_amdgcn_mfma_f32_16x16x32_bf16(sa1, SBf[p], z, 0, 0, 0);
            f32x4 m1 = __builtin_amdgcn_mfma_f32_16x16x32_bf16(ma1, MBf[p], z, 0, 0, 0);

            {
                const float e0 = fast_exp2(s0[0]), e1 = fast_exp2(s0[1]);
                const float e2 = fast_exp2(s0[2]), e3 = fast_exp2(s0[3]);
                const float w0 = e0 * m0[0], w1 = e1 * m0[1];
                const float w2 = e2 * m0[2], w3 = e3 * m0[3];
                u32x2 pp; pp[0] = cvtpk(e0, e1); pp[1] = cvtpk(e2, e3);
                *(u32x2*)(Pb + pWr) = pp;
                u32x4 ww; ww[0] = wsplit(w0); ww[1] = wsplit(w1);
                ww[2] = wsplit(w2); ww[3] = wsplit(w3);
                *(u32x4*)(Wb + wWr) = ww;
            }
            {
                const float e0 = fast_exp2(s1[0]), e1 = fast_exp2(s1[1]);
                const float e2 = fast_exp2(s1[2]), e3 = fast_exp2(s1[3]);
                const float w0 = e0 * m1[0], w1 = e1 * m1[1];
                const float w2 = e2 * m1[2], w3 = e3 * m1[3];
                u32x2 pp; pp[0] = cvtpk(e0, e1); pp[1] = cvtpk(e2, e3);
                *(u32x2*)(Pb + pWr + 16) = pp;
                u32x4 ww; ww[0] = wsplit(w0); ww[1] = wsplit(w1);
                ww[2] = wsplit(w2); ww[3] = wsplit(w3);
                *(u32x4*)(Wb + wWr + 32) = ww;
            }
            const s16x8 pbf = *(const s16x8*)(Pb + pRd);
            const s16x8 wb0 = *(const s16x8*)(Wb + wRd);
            const s16x8 wb1 = *(const s16x8*)(Wb + wRd + 32);
            accG[p] = __builtin_amdgcn_mfma_f32_16x16x32_bf16(mta, pbf, accG[p], 0, 0, 0);
            accF[p] = __builtin_amdgcn_mfma_f32_16x16x32_bf16(fa0, wb0, accF[p], 0, 0, 0);
            accF[p] = __builtin_amdgcn_mfma_f32_16x16x32_bf16(fa1, wb1, accF[p], 0, 0, 0);
        }
    }

    // epilogue: fold rowgroup1 into rowgroup0 (shfl), apply final formulas,
    // store 6 floats per (seg, i) -> part[seg][comp][N]
    #pragma unroll
    for (int p = 0; p < PANELS; ++p) {
        const f32x4 g = accG[p], f = accF[p];
        const float g4 = __shfl_xor((float)g[0], 16);   // row4 = G_lm_y
        const float g5 = __shfl_xor((float)g[1], 16);   // row5 = G_lm_z
        const float f4 = __shfl_xor((float)f[0], 16);   // row4 = Swxl_x
        const float f5 = __shfl_xor((float)f[1], 16);   // row5 = Swxl_y
        const float f6 = __shfl_xor((float)f[2], 16);   // row6 = Swxl_z
        if (lgrp == 0) {
            const int i = ibase[p];
            const float Gx = 2.f * (g[0] + g[3]);       // hm_x + lm_x
            const float Gy = 2.f * (g[1] + g4);
            const float Gz = 2.f * (g[2] + g5);
            const float Sw = f[3];
            const float Fx = 400.f * (pos[3*i+0] * Sw - (f[0] + f4));
            const float Fy = 400.f * (pos[3*i+1] * Sw - (f[1] + f5));
            const float Fz = 400.f * (pos[3*i+2] * Sw - (f[2] + f6));
            float* pp = part + (size_t)seg * 6 * N;
            pp[0*N+i] = Fx; pp[1*N+i] = Fy; pp[2*N+i] = Fz;
            pp[3*N+i] = Gx; pp[4*N+i] = Gy; pp[5*N+i] = Gz;
        }
    }
}

// ---------------- reduce: sum 6 floats over G segs ----------------
__global__ __launch_bounds__(BLOCK)
void lddmm_reduce(const float* __restrict__ part, float* __restrict__ out, int N, int G)
{
    const int i = blockIdx.x * BLOCK + threadIdx.x;
    if (i >= N) return;
    float s[6] = {};
    for (int g = 0; g < G; ++g) {
        const float* p = part + (size_t)g * 6 * N;
        #pragma unroll
        for (int c = 0; c < 6; ++c) s[c] += p[c * N + i];
    }
    out[3*i+0] = s[0]; out[3*i+1] = s[1]; out[3*i+2] = s[2];
    float* o2 = out + (size_t)N * 3;
    o2[3*i+0] = s[3]; o2[3*i+1] = s[4]; o2[3*i+2] = s[5];
}

extern "C" void kernel_launch(void* const* d_in, const int* in_sizes, int n_in,
                              void* d_out, int out_size, void* d_ws, size_t ws_size,
                              hipStream_t stream) {
    const float* mom = (const float*)d_in[0];
    const float* pos = (const float*)d_in[1];
    float* out = (float*)d_out;
    const int N = in_sizes[0] / 3;          // 8192 (assumes N % 512 == 0)

    char* base = (char*)d_ws;
    size_t off = 0;
    ushort* pSA   = (ushort*)(base + off); off += (size_t)N * 64;
    ushort* pSB   = (ushort*)(base + off); off += (size_t)N * 64;
    ushort* pMA   = (ushort*)(base + off); off += (size_t)N * 64;
    ushort* pMB   = (ushort*)(base + off); off += (size_t)N * 64;
    ushort* momTA = (ushort*)(base + off); off += (size_t)N * 32;   // [N/32][16][32]
    ushort* xTFA  = (ushort*)(base + off); off += (size_t)N * 64;   // [N/16][16][32]

    int G = 32;
    while (G > 1 && ((N / G) % 32 != 0 ||
           off + (size_t)G * 6 * N * sizeof(float) > ws_size)) G >>= 1;
    float* part = (float*)(base + off);

    const int nb = (N + BLOCK - 1) / BLOCK;
    lddmm_prep<<<dim3(nb), dim3(BLOCK), 0, stream>>>(mom, pos, pSA, pSB, pMA, pMB,
                                                     momTA, xTFA, N);
    lddmm_mfma<<<dim3((N / IPB) * G), dim3(BLOCK), 0, stream>>>(
        pSA, pSB, pMA, pMB, momTA, xTFA, pos, part, N, G);
    lddmm_reduce<<<dim3(nb), dim3(BLOCK), 0, stream>>>(part, out, N, G);
}

// Round 10
// 46.310 us; speedup vs baseline: 1.4783x; 1.0140x over previous
//
#include <hip/hip_runtime.h>
#include <stdint.h>

// LDDMM Hamiltonian evolution via MFMA — R10: ZERO-LDS edition.
//   out0 = -dH/dpos = 400 * sum_j K_ij (m_i.m_j)(x_i - x_j)
//   out1 =  dH/dmom = 2   * sum_j K_ij m_j ,  K = exp(-100*||x_i-x_j||^2)
//
// Gram-form S/M MFMAs (validated R8/R9, absmax 0.0156). R9's LDS bounce
// (C-frag -> B-frag relayout, 7 DS ops/panel-iter = 15 µs LDS-pipe floor)
// is replaced by a K-PERMUTATION: with k = 8*lgrp + 4*half + r (j =
// 16*half + 4*lgrp + r), the B-fragment of P/W is the lane's OWN C-frag
// values packed via v_cvt_pk_bf16_f32 — no LDS, no barriers, no lgkmcnt.
// The same permutation is applied to momTA / xTFA columns at prep time.
// Kernel = global b128 loads (L2-resident packs) + MFMA + exp/pack VALU.

typedef unsigned short ushort;
typedef unsigned int uint;
typedef short  s16x8 __attribute__((ext_vector_type(8)));
typedef float  f32x4 __attribute__((ext_vector_type(4)));
typedef uint   u32x4 __attribute__((ext_vector_type(4)));

constexpr int BLOCK  = 256;
constexpr int WAVES  = 4;
constexpr int PANELS = 8;                 // i-panels (16 i each) per wave
constexpr int IPW    = PANELS * 16;       // 128 i per wave
constexpr int IPB    = WAVES * IPW;       // 512 i per block

constexpr double S_Dd      = 12.011224087864498;   // sqrt(100*log2(e))
constexpr float  SCALE_POS = (float)S_Dd;

__device__ __forceinline__ float fast_exp2(float x) {
#if __has_builtin(__builtin_amdgcn_exp2f)
    return __builtin_amdgcn_exp2f(x);
#else
    return exp2f(x);
#endif
}
__device__ __forceinline__ ushort bf16r(float f) {      // RNE f32->bf16
    uint u = __float_as_uint(f);
    uint r = u + 0x7FFFu + ((u >> 16) & 1u);
    return (ushort)(r >> 16);
}
__device__ __forceinline__ float bf2f(ushort s) {
    return __uint_as_float(((uint)s) << 16);
}
__device__ __forceinline__ uint cvtpk(float a, float b) {  // lo=bf16(a), hi=bf16(b)
    uint r;
    asm("v_cvt_pk_bf16_f32 %0, %1, %2" : "=v"(r) : "v"(a), "v"(b));
    return r;
}
__device__ __forceinline__ uint wsplit(float w) {       // lo=wh, hi=bf16(w-wh)
    float wh = __uint_as_float(__float_as_uint(w) & 0xFFFF0000u);
    return cvtpk(wh, w - wh);
}
__device__ __forceinline__ s16x8 as_frag(u32x4 v) { return *(s16x8*)&v; }

// ---------------- prep: build all bf16 packs ----------------
__global__ __launch_bounds__(BLOCK)
void lddmm_prep(const float* __restrict__ mom, const float* __restrict__ pos,
                ushort* __restrict__ pSA, ushort* __restrict__ pSB,
                ushort* __restrict__ pMA, ushort* __restrict__ pMB,
                ushort* __restrict__ momTA, ushort* __restrict__ xTFA, int N)
{
    const int n = blockIdx.x * BLOCK + threadIdx.x;
    if (n >= N) return;
    float x[3], m[3];
    #pragma unroll
    for (int c = 0; c < 3; ++c) { x[c] = pos[3 * n + c]; m[c] = mom[3 * n + c]; }

    ushort h[3], l[3], h2[3], l2[3], r2[3];
    float  D = 0.f;
    #pragma unroll
    for (int c = 0; c < 3; ++c) {
        const float X = SCALE_POS * x[c];
        h[c] = bf16r(X);                  const float hf = bf2f(h[c]);
        l[c] = bf16r(X - hf);             const float lf = bf2f(l[c]);
        const float rf = bf2f(bf16r(X - hf - lf));
        h2[c] = bf16r(2.f * hf);
        l2[c] = bf16r(2.f * lf);
        r2[c] = bf16r(2.f * rf);
        D -= X * X;
    }
    const ushort Dh = bf16r(D);           const float Dhf = bf2f(Dh);
    const ushort Dl = bf16r(D - Dhf);     const float Dlf = bf2f(Dl);
    const ushort Dr = bf16r(D - Dhf - Dlf);
    ushort hm[3], lm[3], xh[3], xl[3];
    #pragma unroll
    for (int c = 0; c < 3; ++c) {
        hm[c] = bf16r(m[c]); lm[c] = bf16r(m[c] - bf2f(hm[c]));
        xh[c] = bf16r(x[c]); xl[c] = bf16r(x[c] - bf2f(xh[c]));
    }
    const ushort ONE = 0x3F80;

    // S-pack: sum_k A_k B_k = 2<(h+l+r)_j,(h+l+r)_i> + Dj + Di  (err ~2e-5)
    ushort sa[32] = {}; ushort sb[32] = {};
    #pragma unroll
    for (int c = 0; c < 3; ++c) {
        sa[0+c]=h2[c];  sb[0+c]=h[c];
        sa[3+c]=l2[c];  sb[3+c]=h[c];
        sa[6+c]=h2[c];  sb[6+c]=l[c];
        sa[9+c]=l2[c];  sb[9+c]=l[c];
        sa[18+c]=r2[c]; sb[18+c]=h[c];
        sa[21+c]=h[c];  sb[21+c]=r2[c];
    }
    sa[12]=Dh; sa[13]=Dl; sa[14]=Dr; sb[12]=ONE; sb[13]=ONE; sb[14]=ONE;
    sa[15]=ONE; sa[16]=ONE; sa[17]=ONE; sb[15]=Dh; sb[16]=Dl; sb[17]=Dr;

    ushort ma[32] = {}; ushort mb[32] = {};
    #pragma unroll
    for (int c = 0; c < 3; ++c) {
        ma[0+c]=hm[c]; mb[0+c]=hm[c];
        ma[3+c]=lm[c]; mb[3+c]=hm[c];
        ma[6+c]=hm[c]; mb[6+c]=lm[c];
        ma[9+c]=lm[c]; mb[9+c]=lm[c];
    }

    u32x4* oSA = (u32x4*)(pSA + (size_t)n * 32);
    u32x4* oSB = (u32x4*)(pSB + (size_t)n * 32);
    u32x4* oMA = (u32x4*)(pMA + (size_t)n * 32);
    u32x4* oMB = (u32x4*)(pMB + (size_t)n * 32);
    #pragma unroll
    for (int k = 0; k < 4; ++k) {
        oSA[k] = ((u32x4*)sa)[k]; oSB[k] = ((u32x4*)sb)[k];
        oMA[k] = ((u32x4*)ma)[k]; oMB[k] = ((u32x4*)mb)[k];
    }

    // momT A-tile with K-PERM: j = 16*half + 4*g + r  ->  k = 8*g + 4*half + r
    // [tile=n>>5][row d][k]; rows 0-2=hm, 3-5=lm, 6-15=0
    {
        const int g = (n >> 2) & 3, half = (n >> 4) & 1, r = n & 3;
        const int k = 8 * g + 4 * half + r;
        ushort* q = momTA + (size_t)(n >> 5) * 512 + k;
        q[0*32]=hm[0]; q[1*32]=hm[1]; q[2*32]=hm[2];
        q[3*32]=lm[0]; q[4*32]=lm[1]; q[5*32]=lm[2];
        #pragma unroll
        for (int rr = 6; rr < 16; ++rr) q[rr*32] = 0;
    }
    // xTF A-tile with K-PERM (w-split duplication): j' = n&15 = 4*g + r ->
    // k = 8*g + 2*r + p, p in {0,1} (wh/wl slots). [tile=n>>4][row][32]
    // rows 0-2=xh, 3=1, 4-6=xl, 7-15=0
    {
        const int g = (n >> 2) & 3, r = n & 3;
        ushort* q = xTFA + (size_t)(n >> 4) * 512 + 8 * g + 2 * r;
        #pragma unroll
        for (int p = 0; p < 2; ++p) {
            q[0*32+p]=xh[0]; q[1*32+p]=xh[1]; q[2*32+p]=xh[2];
            q[3*32+p]=ONE;
            q[4*32+p]=xl[0]; q[5*32+p]=xl[1]; q[6*32+p]=xl[2];
            #pragma unroll
            for (int rr = 7; rr < 16; ++rr) q[rr*32+p] = 0;
        }
    }
}

// ---------------- main: MFMA, zero LDS, zero barriers ----------------
__global__ __launch_bounds__(BLOCK, 2)
void lddmm_mfma(const ushort* __restrict__ pSA, const ushort* __restrict__ pSB,
                const ushort* __restrict__ pMA, const ushort* __restrict__ pMB,
                const ushort* __restrict__ momTA, const ushort* __restrict__ xTFA,
                const float* __restrict__ pos, float* __restrict__ part,
                int N, int G)
{
    const int tid  = threadIdx.x;
    const int w    = tid >> 6;
    const int lane = tid & 63;
    const int lrow = lane & 15;
    const int lgrp = lane >> 4;

    const int bid  = blockIdx.x;
    const int seg  = bid % G;
    const int iblk = bid / G;
    const int segLen = N / G;            // multiple of 32
    const int jseg0  = seg * segLen;
    const int nsup   = segLen >> 5;

    s16x8 SBf[PANELS], MBf[PANELS];
    int ibase[PANELS];
    #pragma unroll
    for (int p = 0; p < PANELS; ++p) {
        const int i = iblk * IPB + w * IPW + p * 16 + lrow;
        ibase[p] = i;
        SBf[p] = *(const s16x8*)(pSB + (size_t)i * 32 + lgrp * 8);
        MBf[p] = *(const s16x8*)(pMB + (size_t)i * 32 + lgrp * 8);
    }
    const f32x4 z = {0.f, 0.f, 0.f, 0.f};
    f32x4 accG[PANELS], accF[PANELS];
    #pragma unroll
    for (int p = 0; p < PANELS; ++p) { accG[p] = z; accF[p] = z; }

    const ushort* saP = pSA + (size_t)jseg0 * 32 + lrow * 32 + lgrp * 8;
    const ushort* maP = pMA + (size_t)jseg0 * 32 + lrow * 32 + lgrp * 8;
    const ushort* mtP = momTA + (size_t)(jseg0 >> 5) * 512 + lrow * 32 + lgrp * 8;
    const ushort* faP = xTFA  + (size_t)(jseg0 >> 4) * 512 + lrow * 32 + lgrp * 8;

    for (int s = 0; s < nsup; ++s) {
        const s16x8 sa0 = *(const s16x8*)(saP);
        const s16x8 sa1 = *(const s16x8*)(saP + 512);
        const s16x8 ma0 = *(const s16x8*)(maP);
        const s16x8 ma1 = *(const s16x8*)(maP + 512);
        const s16x8 mta = *(const s16x8*)(mtP);
        const s16x8 fa0 = *(const s16x8*)(faP);
        const s16x8 fa1 = *(const s16x8*)(faP + 512);
        saP += 1024; maP += 1024; mtP += 512; faP += 1024;

        #pragma unroll
        for (int p = 0; p < PANELS; ++p) {
            f32x4 s0 = __builtin_amdgcn_mfma_f32_16x16x32_bf16(sa0, SBf[p], z, 0, 0, 0);
            f32x4 m0 = __builtin_amdgcn_mfma_f32_16x16x32_bf16(ma0, MBf[p], z, 0, 0, 0);
            f32x4 s1 = __builtin_amdgcn_mfma_f32_16x16x32_bf16(sa1, SBf[p], z, 0, 0, 0);
            f32x4 m1 = __builtin_amdgcn_mfma_f32_16x16x32_bf16(ma1, MBf[p], z, 0, 0, 0);

            const float e00 = fast_exp2(s0[0]), e01 = fast_exp2(s0[1]);
            const float e02 = fast_exp2(s0[2]), e03 = fast_exp2(s0[3]);
            const float e10 = fast_exp2(s1[0]), e11 = fast_exp2(s1[1]);
            const float e12 = fast_exp2(s1[2]), e13 = fast_exp2(s1[3]);

            // P B-frag: lane-local repack (k-perm makes C-frag == B-frag source)
            u32x4 pf;
            pf[0] = cvtpk(e00, e01); pf[1] = cvtpk(e02, e03);
            pf[2] = cvtpk(e10, e11); pf[3] = cvtpk(e12, e13);
            // W B-frags: (wh,wl) per j in 2 duplicated k-slots, lane-local
            u32x4 w0, w1;
            w0[0] = wsplit(e00 * m0[0]); w0[1] = wsplit(e01 * m0[1]);
            w0[2] = wsplit(e02 * m0[2]); w0[3] = wsplit(e03 * m0[3]);
            w1[0] = wsplit(e10 * m1[0]); w1[1] = wsplit(e11 * m1[1]);
            w1[2] = wsplit(e12 * m1[2]); w1[3] = wsplit(e13 * m1[3]);

            accG[p] = __builtin_amdgcn_mfma_f32_16x16x32_bf16(mta, as_frag(pf), accG[p], 0, 0, 0);
            accF[p] = __builtin_amdgcn_mfma_f32_16x16x32_bf16(fa0, as_frag(w0), accF[p], 0, 0, 0);
            accF[p] = __builtin_amdgcn_mfma_f32_16x16x32_bf16(fa1, as_frag(w1), accF[p], 0, 0, 0);
        }
    }

    // epilogue: fold rowgroup1 into rowgroup0 (shfl), apply final formulas,
    // store 6 floats per (seg, i) -> part[seg][comp][N]
    #pragma unroll
    for (int p = 0; p < PANELS; ++p) {
        const f32x4 g = accG[p], f = accF[p];
        const float g4 = __shfl_xor((float)g[0], 16);   // row4 = G_lm_y
        const float g5 = __shfl_xor((float)g[1], 16);   // row5 = G_lm_z
        const float f4 = __shfl_xor((float)f[0], 16);   // row4 = Swxl_x
        const float f5 = __shfl_xor((float)f[1], 16);   // row5 = Swxl_y
        const float f6 = __shfl_xor((float)f[2], 16);   // row6 = Swxl_z
        if (lgrp == 0) {
            const int i = ibase[p];
            const float Gx = 2.f * (g[0] + g[3]);       // hm_x + lm_x
            const float Gy = 2.f * (g[1] + g4);
            const float Gz = 2.f * (g[2] + g5);
            const float Sw = f[3];
            const float Fx = 400.f * (pos[3*i+0] * Sw - (f[0] + f4));
            const float Fy = 400.f * (pos[3*i+1] * Sw - (f[1] + f5));
            const float Fz = 400.f * (pos[3*i+2] * Sw - (f[2] + f6));
            float* pp = part + (size_t)seg * 6 * N;
            pp[0*N+i] = Fx; pp[1*N+i] = Fy; pp[2*N+i] = Fz;
            pp[3*N+i] = Gx; pp[4*N+i] = Gy; pp[5*N+i] = Gz;
        }
    }
}

// ---------------- reduce: sum 6 floats over G segs ----------------
__global__ __launch_bounds__(BLOCK)
void lddmm_reduce(const float* __restrict__ part, float* __restrict__ out, int N, int G)
{
    const int i = blockIdx.x * BLOCK + threadIdx.x;
    if (i >= N) return;
    float s[6] = {};
    for (int g = 0; g < G; ++g) {
        const float* p = part + (size_t)g * 6 * N;
        #pragma unroll
        for (int c = 0; c < 6; ++c) s[c] += p[c * N + i];
    }
    out[3*i+0] = s[0]; out[3*i+1] = s[1]; out[3*i+2] = s[2];
    float* o2 = out + (size_t)N * 3;
    o2[3*i+0] = s[3]; o2[3*i+1] = s[4]; o2[3*i+2] = s[5];
}

extern "C" void kernel_launch(void* const* d_in, const int* in_sizes, int n_in,
                              void* d_out, int out_size, void* d_ws, size_t ws_size,
                              hipStream_t stream) {
    const float* mom = (const float*)d_in[0];
    const float* pos = (const float*)d_in[1];
    float* out = (float*)d_out;
    const int N = in_sizes[0] / 3;          // 8192 (assumes N % 512 == 0)

    char* base = (char*)d_ws;
    size_t off = 0;
    ushort* pSA   = (ushort*)(base + off); off += (size_t)N * 64;
    ushort* pSB   = (ushort*)(base + off); off += (size_t)N * 64;
    ushort* pMA   = (ushort*)(base + off); off += (size_t)N * 64;
    ushort* pMB   = (ushort*)(base + off); off += (size_t)N * 64;
    ushort* momTA = (ushort*)(base + off); off += (size_t)N * 32;   // [N/32][16][32]
    ushort* xTFA  = (ushort*)(base + off); off += (size_t)N * 64;   // [N/16][16][32]

    int G = 32;
    while (G > 1 && ((N / G) % 32 != 0 ||
           off + (size_t)G * 6 * N * sizeof(float) > ws_size)) G >>= 1;
    float* part = (float*)(base + off);

    const int nb = (N + BLOCK - 1) / BLOCK;
    lddmm_prep<<<dim3(nb), dim3(BLOCK), 0, stream>>>(mom, pos, pSA, pSB, pMA, pMB,
                                                     momTA, xTFA, N);
    lddmm_mfma<<<dim3((N / IPB) * G), dim3(BLOCK), 0, stream>>>(
        pSA, pSB, pMA, pMB, momTA, xTFA, pos, part, N, G);
    lddmm_reduce<<<dim3(nb), dim3(BLOCK), 0, stream>>>(part, out, N, G);
}